// Round 7
// baseline (268.203 us; speedup 1.0000x reference)
//
#include <hip/hip_runtime.h>
#include <math.h>

#define Bq 8
#define Sq 2048
#define Hq 1024
#define QT 32          // attn rows per block (4 waves x 8 rows)
#define INV_SQRT_H (1.0f / 32.0f)

typedef float f32x4 __attribute__((ext_vector_type(4)));

__device__ __forceinline__ float waveReduceSum(float v) {
#pragma unroll
    for (int off = 32; off > 0; off >>= 1) v += __shfl_xor(v, off, 64);
    return v;
}

// ---------------------------------------------------------------------------
// prep: blocks 0..31 -> wq_eff[h] = sum_o Wq[o,h]*Wk[o]  (atomic o-chunks)
//       block  32    -> cb = (bq . Wk)/sqrt(H)
//       blocks 33..40-> per-batch min/max of sqi
// ---------------------------------------------------------------------------
__global__ void k_prep(const float* __restrict__ Wq, const float* __restrict__ Wk,
                       const float* __restrict__ bq, const float* __restrict__ sqi,
                       float* __restrict__ wq_eff, float* __restrict__ cb,
                       float* __restrict__ ext) {
    int bid = blockIdx.x, t = threadIdx.x;
    int wid = t >> 6, lane = t & 63;
    if (bid < 32) {
        int hc = bid & 3, oc = bid >> 2;
        int h = hc * 256 + t, o0 = oc * 128;
        float acc = 0.f;
#pragma unroll 4
        for (int o = 0; o < 128; ++o)
            acc += Wq[(size_t)(o0 + o) * Hq + h] * Wk[o0 + o];
        atomicAdd(&wq_eff[h], acc);
    } else if (bid == 32) {
        float acc = 0.f;
#pragma unroll
        for (int j = 0; j < 4; ++j) acc += bq[t * 4 + j] * Wk[t * 4 + j];
        acc = waveReduceSum(acc);
        __shared__ float red[4];
        if (lane == 0) red[wid] = acc;
        __syncthreads();
        if (t == 0) *cb = (red[0] + red[1] + red[2] + red[3]) * INV_SQRT_H;
    } else {
        int b = bid - 33;
        float mn = 1e30f, mx = -1e30f;
        for (int j = t; j < Sq; j += 256) {
            float v = sqi[b * Sq + j];
            mn = fminf(mn, v);
            mx = fmaxf(mx, v);
        }
#pragma unroll
        for (int off = 32; off > 0; off >>= 1) {
            mn = fminf(mn, __shfl_xor(mn, off, 64));
            mx = fmaxf(mx, __shfl_xor(mx, off, 64));
        }
        __shared__ float smn[4], smx[4];
        if (lane == 0) { smn[wid] = mn; smx[wid] = mx; }
        __syncthreads();
        if (t == 0) {
            ext[b]      = fminf(fminf(smn[0], smn[1]), fminf(smn[2], smn[3]));
            ext[Bq + b] = fmaxf(fmaxf(smx[0], smx[1]), fmaxf(smx[2], smx[3]));
        }
    }
}

// attn[b,q,:] = softmax( a[b,q]*sqi[b,:] ); a = ((hid+pos).wq_eff)/32 + cb.
// Wave owns 8 rows end-to-end; fused column-sums via LDS atomics (2 barriers).
__global__ void __launch_bounds__(256) k_attn(
        const float* __restrict__ hidden, const float* __restrict__ pos,
        const float* __restrict__ wq_eff, const float* __restrict__ cbp,
        const float* __restrict__ sqi, const float* __restrict__ ext,
        float* __restrict__ attn, float* __restrict__ wcol) {
    int b = blockIdx.y, qt = blockIdx.x, t = threadIdx.x;
    int wid = t >> 6, lane = t & 63;
    __shared__ float sqi_s[Sq];
    __shared__ float colsum[Sq];
    {
        const float4* sp = (const float4*)(sqi + b * Sq);
        float4* ds = (float4*)sqi_s;
        ds[t]       = sp[t];
        ds[256 + t] = sp[256 + t];
        float4* cz = (float4*)colsum;
        cz[t]       = make_float4(0.f, 0.f, 0.f, 0.f);
        cz[256 + t] = make_float4(0.f, 0.f, 0.f, 0.f);
    }
    float smin = ext[b], smax = ext[Bq + b];
    float cbv = *cbp;

    // ---- a-phase: wave computes a for its 8 rows ((hid+pos).wq_eff)/32 + cb
    const float4* wp = (const float4*)wq_eff;
    float4 w0 = wp[lane], w1 = wp[lane + 64], w2 = wp[lane + 128], w3 = wp[lane + 192];
    int q0 = qt * QT + wid * 8;
    float a[8];
#pragma unroll
    for (int r = 0; r < 8; ++r) {
        const float4* hp = (const float4*)(hidden + (size_t)(b * Sq + q0 + r) * Hq);
        const float4* pp = (const float4*)(pos + (size_t)(q0 + r) * Hq);
        float4 h0 = hp[lane], h1 = hp[lane + 64], h2 = hp[lane + 128], h3 = hp[lane + 192];
        float4 p0 = pp[lane], p1 = pp[lane + 64], p2 = pp[lane + 128], p3 = pp[lane + 192];
        float d = (h0.x + p0.x) * w0.x + (h0.y + p0.y) * w0.y + (h0.z + p0.z) * w0.z + (h0.w + p0.w) * w0.w
                + (h1.x + p1.x) * w1.x + (h1.y + p1.y) * w1.y + (h1.z + p1.z) * w1.z + (h1.w + p1.w) * w1.w
                + (h2.x + p2.x) * w2.x + (h2.y + p2.y) * w2.y + (h2.z + p2.z) * w2.z + (h2.w + p2.w) * w2.w
                + (h3.x + p3.x) * w3.x + (h3.y + p3.y) * w3.y + (h3.z + p3.z) * w3.z + (h3.w + p3.w) * w3.w;
        d = waveReduceSum(d);
        a[r] = d * INV_SQRT_H + cbv;
    }
    __syncthreads();   // sqi_s + zeroed colsum ready

    // ---- softmax phase: per row, lane covers 8 float4 chunks (32 cols)
    const float4* ss = (const float4*)sqi_s;
    float4 ca[8];
#pragma unroll
    for (int c = 0; c < 8; ++c) ca[c] = make_float4(0.f, 0.f, 0.f, 0.f);

    for (int r = 0; r < 8; ++r) {
        float aa = a[r];
        float m = (aa > 0.f) ? aa * smax : aa * smin;   // exact row max
        float4 e[8];
        float s = 0.f;
#pragma unroll
        for (int c = 0; c < 8; ++c) {
            float4 sv = ss[lane + 64 * c];
            e[c].x = __expf(aa * sv.x - m);
            e[c].y = __expf(aa * sv.y - m);
            e[c].z = __expf(aa * sv.z - m);
            e[c].w = __expf(aa * sv.w - m);
            s += e[c].x + e[c].y + e[c].z + e[c].w;
        }
        s = waveReduceSum(s);
        float rinv = 1.0f / s;
        f32x4* orow = (f32x4*)(attn + (size_t)(b * Sq + q0 + r) * Sq);
#pragma unroll
        for (int c = 0; c < 8; ++c) {
            f32x4 p;
            p.x = e[c].x * rinv; p.y = e[c].y * rinv;
            p.z = e[c].z * rinv; p.w = e[c].w * rinv;
            __builtin_nontemporal_store(p, &orow[lane + 64 * c]);
            ca[c].x += p.x; ca[c].y += p.y; ca[c].z += p.z; ca[c].w += p.w;
        }
    }

    // ---- column-sum combine: LDS atomics (ds_add_f32), then global atomics
#pragma unroll
    for (int c = 0; c < 8; ++c) {
        int base = (lane + 64 * c) * 4;
        atomicAdd(&colsum[base + 0], ca[c].x);
        atomicAdd(&colsum[base + 1], ca[c].y);
        atomicAdd(&colsum[base + 2], ca[c].z);
        atomicAdd(&colsum[base + 3], ca[c].w);
    }
    __syncthreads();
#pragma unroll
    for (int j = 0; j < 8; ++j)
        atomicAdd(&wcol[b * Sq + j * 256 + t], colsum[j * 256 + t]);
}

// y[b,h] = sum_kk (wcol[b,kk]/S) * (hidden[b,kk,h] + pos[kk,h])
__global__ void k_y(const float* __restrict__ hidden, const float* __restrict__ pos,
                    const float* __restrict__ wcol, float* __restrict__ y) {
    int b = blockIdx.y, kc = blockIdx.x, t = threadIdx.x;
    int kk0 = kc * 32;             // 32 rows per block, 64 blocks per batch
    float4 acc = {0, 0, 0, 0};
#pragma unroll 4
    for (int i = 0; i < 32; ++i) {
        int kk = kk0 + i;
        float wv = wcol[b * Sq + kk] * (1.0f / Sq);
        float4 hv = ((const float4*)(hidden + ((size_t)(b * Sq + kk)) * Hq))[t];
        float4 pv = ((const float4*)(pos + (size_t)kk * Hq))[t];
        acc.x += wv * (hv.x + pv.x);
        acc.y += wv * (hv.y + pv.y);
        acc.z += wv * (hv.z + pv.z);
        acc.w += wv * (hv.w + pv.w);
    }
    atomicAdd(&y[b * Hq + t * 4 + 0], acc.x);
    atomicAdd(&y[b * Hq + t * 4 + 1], acc.y);
    atomicAdd(&y[b * Hq + t * 4 + 2], acc.z);
    atomicAdd(&y[b * Hq + t * 4 + 3], acc.w);
}

// ctx[b,h] = Wv[h,:] . y[b,:] + bv[h]  -- wave per 4 rows, direct store
__global__ void k_ctx(const float* __restrict__ Wv, const float* __restrict__ bv,
                      const float* __restrict__ y, float* __restrict__ ctx) {
    int b = blockIdx.y, t = threadIdx.x;
    int wid = t >> 6, lane = t & 63;
    __shared__ float4 ys4[Hq / 4];
    ys4[t] = ((const float4*)(y + b * Hq))[t];
    __syncthreads();
    float4 y0 = ys4[lane], y1 = ys4[lane + 64], y2 = ys4[lane + 128], y3 = ys4[lane + 192];
    int h0 = blockIdx.x * 16 + wid * 4;
#pragma unroll
    for (int r = 0; r < 4; ++r) {
        int h = h0 + r;
        const float4* wrow = (const float4*)(Wv + (size_t)h * Hq);
        float4 v0 = wrow[lane], v1 = wrow[lane + 64], v2 = wrow[lane + 128], v3 = wrow[lane + 192];
        float d = v0.x * y0.x + v0.y * y0.y + v0.z * y0.z + v0.w * y0.w
                + v1.x * y1.x + v1.y * y1.y + v1.z * y1.z + v1.w * y1.w
                + v2.x * y2.x + v2.y * y2.y + v2.z * y2.z + v2.w * y2.w
                + v3.x * y3.x + v3.y * y3.y + v3.z * y3.z + v3.w * y3.w;
        d = waveReduceSum(d);
        if (lane == 0) ctx[b * Hq + h] = d + bv[h];
    }
}

extern "C" void kernel_launch(void* const* d_in, const int* in_sizes, int n_in,
                              void* d_out, int out_size, void* d_ws, size_t ws_size,
                              hipStream_t stream) {
    const float* hidden = (const float*)d_in[0];
    const float* sqi    = (const float*)d_in[1];
    const float* pos    = (const float*)d_in[2];
    const float* Wq     = (const float*)d_in[3];
    const float* bq     = (const float*)d_in[4];
    const float* Wk     = (const float*)d_in[5];
    // bk (d_in[6]) shifts every score in a row equally -> cancels in softmax
    const float* Wv     = (const float*)d_in[7];
    const float* bv     = (const float*)d_in[8];

    float* out  = (float*)d_out;
    float* ctx  = out;                    // [B,H]
    float* attn = out + Bq * Hq;          // [B,S,S]

    // workspace layout (floats)
    float* ws     = (float*)d_ws;
    float* wq_eff = ws;                   // 1024
    float* wcol   = ws + 1024;            // 16384
    float* y      = ws + 17408;           // 8192   (zeroed region ends: 25600)
    float* ext    = ws + 25600;           // 16 (min[8], max[8])
    float* cb     = ws + 25616;           // 1

    (void)hipMemsetAsync(ws, 0, 25600 * sizeof(float), stream);    // wq_eff+wcol+y

    k_prep<<<41, 256, 0, stream>>>(Wq, Wk, bq, sqi, wq_eff, cb, ext);
    k_attn<<<dim3(Sq / QT, Bq), 256, 0, stream>>>(hidden, pos, wq_eff, cb,
                                                  sqi, ext, attn, wcol);
    k_y   <<<dim3(64, Bq), 256, 0, stream>>>(hidden, pos, wcol, y);
    k_ctx <<<dim3(Hq / 16, Bq), 256, 0, stream>>>(Wv, bv, y, ctx);
}